// Round 1
// baseline (1174.854 us; speedup 1.0000x reference)
//
#include <hip/hip_runtime.h>
#include <cmath>

#define H 512
#define W 512
#define HW (H * W)
#define NORG 10
#define SS 32
#define CHUNKS 128
#define CH_SAL 0
#define CH_SHP 1
#define CH_SZ 1025
#define CH_HEAT 1027

// ---------------- Kernel A: per-organ chunked argmax over heatmaps ----------------
__global__ __launch_bounds__(256) void k_argmax_partial(const float* __restrict__ feat,
                                                        float* __restrict__ pv,
                                                        int* __restrict__ pi) {
    const int o = blockIdx.y;
    const int chunk = blockIdx.x;
    const int t = threadIdx.x;
    const float* heat = feat + (size_t)(CH_HEAT + o) * HW;
    const int base = chunk * (HW / CHUNKS);

    float best = -INFINITY;
    int bidx = 0x7fffffff;
#pragma unroll
    for (int i = 0; i < (HW / CHUNKS) / 256; ++i) {
        int idx = base + i * 256 + t;
        float v = heat[idx];
        if (v > best || (v == best && idx < bidx)) { best = v; bidx = idx; }
    }

    __shared__ float sv[256];
    __shared__ int si[256];
    sv[t] = best; si[t] = bidx;
    __syncthreads();
    for (int s = 128; s > 0; s >>= 1) {
        if (t < s) {
            float v2 = sv[t + s]; int i2 = si[t + s];
            if (v2 > sv[t] || (v2 == sv[t] && i2 < si[t])) { sv[t] = v2; si[t] = i2; }
        }
        __syncthreads();
    }
    if (t == 0) { pv[o * CHUNKS + chunk] = sv[0]; pi[o * CHUNKS + chunk] = si[0]; }
}

// ------- Kernel B: finalize argmax, compute box metadata, gather 32x32 shapes -------
__global__ __launch_bounds__(128) void k_finalize(const float* __restrict__ feat,
                                                  const float* __restrict__ pv,
                                                  const int* __restrict__ pi,
                                                  int* __restrict__ meta,
                                                  float* __restrict__ shp_ws,
                                                  float* __restrict__ out_centers) {
    const int o = blockIdx.x;
    const int t = threadIdx.x;
    __shared__ float sv[128];
    __shared__ int si[128];
    sv[t] = pv[o * CHUNKS + t];
    si[t] = pi[o * CHUNKS + t];
    __syncthreads();
    for (int s = 64; s > 0; s >>= 1) {
        if (t < s) {
            float v2 = sv[t + s]; int i2 = si[t + s];
            if (v2 > sv[t] || (v2 == sv[t] && i2 < si[t])) { sv[t] = v2; si[t] = i2; }
        }
        __syncthreads();
    }
    const int idx = si[0];

    // gather the organ's 1024 shape-code values (strided 1 MB apart; tiny total)
    for (int k = t; k < 1024; k += 128) {
        shp_ws[o * 1024 + k] = feat[(size_t)(CH_SHP + k) * HW + idx];
    }

    if (t == 0) {
        int px = idx % W;
        int py = idx / W;
        float fh = feat[(size_t)CH_SZ * HW + idx];
        float fw = feat[(size_t)(CH_SZ + 1) * HW + idx];
        int sh = (int)fh; if (sh < 0) sh = -sh; if (sh < 1) sh = 1;
        int sw = (int)fw; if (sw < 0) sw = -sw; if (sw < 1) sw = 1;
        int r0 = py - sh / 2;
        int c0 = px - sw / 2;
        meta[o * 8 + 0] = px;
        meta[o * 8 + 1] = py;
        meta[o * 8 + 2] = sh;
        meta[o * 8 + 3] = sw;
        meta[o * 8 + 4] = r0;
        meta[o * 8 + 5] = c0;
        out_centers[o * 2 + 0] = (float)px;
        out_centers[o * 2 + 1] = (float)py;
    }
}

__device__ __forceinline__ float sigmf(float x) { return 1.0f / (1.0f + __expf(-x)); }

// ------- Kernel C: write size map (float4) + final masks (float4) -------
__global__ __launch_bounds__(256) void k_write(const float* __restrict__ feat,
                                               const int* __restrict__ meta,
                                               const float* __restrict__ shp_ws,
                                               float* __restrict__ out) {
    const int gid = blockIdx.x * blockDim.x + threadIdx.x;
    const int NSIZE4 = (2 * HW) / 4;  // float4 count for the size map

    if (gid < NSIZE4) {
        const float4* in4 = (const float4*)(feat + (size_t)CH_SZ * HW);
        float4 v = in4[gid];
        float4 r;
        int a;
        a = (int)v.x; r.x = (float)(a < 0 ? -a : a);
        a = (int)v.y; r.y = (float)(a < 0 ? -a : a);
        a = (int)v.z; r.z = (float)(a < 0 ? -a : a);
        a = (int)v.w; r.w = (float)(a < 0 ? -a : a);
        ((float4*)out)[gid] = r;
        return;
    }

    const int fid = gid - NSIZE4;          // float4 index into final region (10*HW/4)
    const int o = fid / (HW / 4);
    const int p4 = fid % (HW / 4);
    const int pix = p4 * 4;
    const int R = pix / W;
    const int C0 = pix % W;

    const int sh = meta[o * 8 + 2];
    const int sw = meta[o * 8 + 3];
    const int r0 = meta[o * 8 + 4];
    const int c0 = meta[o * 8 + 5];

    float4 res = make_float4(0.f, 0.f, 0.f, 0.f);
    if (R >= r0 && R < r0 + sh) {
        const float inv_h = (float)SS / (float)sh;
        const float inv_w = (float)SS / (float)sw;
        float sy = ((float)(R - r0) + 0.5f) * inv_h - 0.5f;
        sy = fminf(fmaxf(sy, 0.0f), (float)(SS - 1));
        int y0 = (int)floorf(sy);
        int y1 = min(y0 + 1, SS - 1);
        float wy = sy - (float)y0;
        const float* srow0 = shp_ws + o * 1024 + y0 * SS;
        const float* srow1 = shp_ws + o * 1024 + y1 * SS;
        float* rp = &res.x;
#pragma unroll
        for (int j = 0; j < 4; ++j) {
            int C = C0 + j;
            if (C >= c0 && C < c0 + sw) {
                float sx = ((float)(C - c0) + 0.5f) * inv_w - 0.5f;
                sx = fminf(fmaxf(sx, 0.0f), (float)(SS - 1));
                int x0 = (int)floorf(sx);
                int x1 = min(x0 + 1, SS - 1);
                float wx = sx - (float)x0;
                float v00 = srow0[x0], v01 = srow0[x1];
                float v10 = srow1[x0], v11 = srow1[x1];
                float local = (1.f - wy) * ((1.f - wx) * v00 + wx * v01) +
                              wy * ((1.f - wx) * v10 + wx * v11);
                float sal = feat[(size_t)CH_SAL * HW + pix + j];
                rp[j] = sigmf(local) * sigmf(sal);
            }
        }
    }
    // final region starts at 2*HW + 20 floats = 16B-aligned (524308 % 4 == 0)
    float4* outf = (float4*)(out + 2 * HW + 2 * NORG);
    outf[fid] = res;
}

extern "C" void kernel_launch(void* const* d_in, const int* in_sizes, int n_in,
                              void* d_out, int out_size, void* d_ws, size_t ws_size,
                              hipStream_t stream) {
    const float* feat = (const float*)d_in[0];
    float* out = (float*)d_out;
    char* ws = (char*)d_ws;

    float* pv = (float*)ws;                 // 10*128 floats   = 5120 B
    int* pi = (int*)(ws + 5120);            // 10*128 ints     = 5120 B
    int* meta = (int*)(ws + 10240);         // 10*8 ints       = 320 B
    float* shp_ws = (float*)(ws + 10752);   // 10*1024 floats  = 40960 B

    dim3 gridA(CHUNKS, NORG);
    k_argmax_partial<<<gridA, 256, 0, stream>>>(feat, pv, pi);
    k_finalize<<<NORG, 128, 0, stream>>>(feat, pv, pi, meta, shp_ws, out + 2 * HW);

    const int total4 = (2 * HW) / 4 + (NORG * HW) / 4;  // 786432 threads
    k_write<<<total4 / 256, 256, 0, stream>>>(feat, meta, shp_ws, out);
}